// Round 6
// baseline (222.359 us; speedup 1.0000x reference)
//
#include <hip/hip_runtime.h>
#include <cstddef>

#define CC 256
#define HH 128
#define WW 128
#define HW (HH*WW)          // 16384

typedef __attribute__((ext_vector_type(8))) short short8v;   // 8 bf16
typedef __attribute__((ext_vector_type(4))) float float4v;   // MFMA acc

__device__ __forceinline__ short f2bf(float x) {
    unsigned u = __float_as_uint(x);
    u += 0x7FFFu + ((u >> 16) & 1u);      // RNE to bf16
    return (short)(u >> 16);
}
__device__ __forceinline__ float bf2f(unsigned short s) {
    return __uint_as_float(((unsigned)s) << 16);
}

// ============ Kernel 1: fused pooling + both energies (direct-global MFMA) ====
// grid 512: b = bid&7, grp = bid>>3 (4 c's per block, register-accumulated).
// block 256 (4 waves). NO t2 LDS staging: MFMA A/B fragments load straight
// from global in fragment shape; pools are in-lane hsum8 of the fragments.
// Only the 16x128 keys go through LDS (8 KB, 2 barriers per c).
__global__ __launch_bounds__(256, 2) void fused_pool_energy(
    const float* __restrict__ t1, const float* __restrict__ t2,
    unsigned short* __restrict__ valHbf, float* __restrict__ valW,
    float* __restrict__ PH, float* __restrict__ PW)
{
    __shared__ __align__(16) short kH [16*128];   // [k][w]  swz (k&7)<<3   4KB
    __shared__ __align__(16) short kWT[16*128];   // [kw][h] swz (kw&7)<<3  4KB

    const int bid = blockIdx.x;
    const int b = bid & 7, grp = bid >> 3;
    const int tid = threadIdx.x;
    const int l  = tid & 63;
    const int wv = tid >> 6;            // wave 0..3
    const int lr = l & 15;              // fragment row/col lane index
    const int lc = l >> 4;              // fragment chunk 0..3

    float4v accH[2] = {{0.f,0.f,0.f,0.f},{0.f,0.f,0.f,0.f}};  // D[h][k] tiles
    float4v accW[2] = {{0.f,0.f,0.f,0.f},{0.f,0.f,0.f,0.f}};  // D[k][w] tiles
    short8v kHreg[4], kWreg[4];

    for (int ci = 0; ci < 4; ++ci) {
        const int c = grp*4 + ci;
        const int bc = b*CC + c;
        const float* t1c = t1 + (size_t)bc * HW;
        const float* t2c = t2 + (size_t)bc * HW;

        __syncthreads();    // protect key LDS vs previous iteration's readers

        // ---- T1 row pass: W-pool -> kWT (in-lane hsum8 of row fragments) ----
        #pragma unroll
        for (int t = 0; t < 2; ++t) {
            const int row = (wv*2 + t)*16 + lr;
            #pragma unroll
            for (int ws = 0; ws < 4; ++ws) {
                const float4* p = (const float4*)(t1c + (size_t)row * WW) + ws*8 + lc*2;
                float4 a = p[0], q = p[1];
                float s = a.x+a.y+a.z+a.w + q.x+q.y+q.z+q.w;
                const int kw = ws*4 + lc;
                kWT[kw*128 + (row ^ ((kw&7)<<3))] = f2bf(s * 0.125f);
            }
        }
        // ---- T1 col pass: H-pool -> kH (in-lane 8-row sum, cache-hot) ----
        #pragma unroll
        for (int t = 0; t < 2; ++t) {
            const int col = (wv*2 + t)*16 + lr;
            #pragma unroll
            for (int hs = 0; hs < 4; ++hs) {
                const int rb = hs*32 + lc*8;
                float s = 0.f;
                #pragma unroll
                for (int j = 0; j < 8; ++j)
                    s += t1c[(size_t)(rb + j)*WW + col];
                const int kh = hs*4 + lc;
                kH[kh*128 + (col ^ ((kh&7)<<3))] = f2bf(s * 0.125f);
            }
        }
        __syncthreads();

        // ---- key fragments -> registers (b128, swizzled, 2-way free) ----
        #pragma unroll
        for (int ws = 0; ws < 4; ++ws)
            kHreg[ws] = *(const short8v*)&kH[lr*128 + ((ws*32 + lc*8) ^ ((lr&7)<<3))];
        #pragma unroll
        for (int hs = 0; hs < 4; ++hs)
            kWreg[hs] = *(const short8v*)&kWT[lr*128 + ((hs*32 + lc*8) ^ ((lr&7)<<3))];

        // ---- T2 col pass: W-branch B-frags + valH (first touch of t2) ----
        #pragma unroll
        for (int t = 0; t < 2; ++t) {
            const int col = (wv*2 + t)*16 + lr;       // w
            #pragma unroll
            for (int hs = 0; hs < 4; ++hs) {
                const int rb = hs*32 + lc*8;
                float x[8];
                #pragma unroll
                for (int j = 0; j < 8; ++j)
                    x[j] = t2c[(size_t)(rb + j)*WW + col];
                float s = x[0]+x[1]+x[2]+x[3]+x[4]+x[5]+x[6]+x[7];
                short8v bf;
                #pragma unroll
                for (int j = 0; j < 8; ++j) bf[j] = f2bf(x[j]);
                const int kh = hs*4 + lc;
                valHbf[(size_t)bc*2048 + kh*128 + col] = (unsigned short)f2bf(s * 0.125f);
                accW[t] = __builtin_amdgcn_mfma_f32_16x16x32_bf16(kWreg[hs], bf, accW[t], 0, 0, 0);
            }
        }
        // ---- T2 row pass: H-branch A-frags + valW (cache-hot) ----
        #pragma unroll
        for (int t = 0; t < 2; ++t) {
            const int row = (wv*2 + t)*16 + lr;       // h
            #pragma unroll
            for (int ws = 0; ws < 4; ++ws) {
                const float4* p = (const float4*)(t2c + (size_t)row * WW) + ws*8 + lc*2;
                float4 a = p[0], q = p[1];
                float s = a.x+a.y+a.z+a.w + q.x+q.y+q.z+q.w;
                short8v af;
                af[0]=f2bf(a.x); af[1]=f2bf(a.y); af[2]=f2bf(a.z); af[3]=f2bf(a.w);
                af[4]=f2bf(q.x); af[5]=f2bf(q.y); af[6]=f2bf(q.z); af[7]=f2bf(q.w);
                valW[(size_t)bc*2048 + (size_t)row*16 + ws*4 + lc] = s * 0.125f;
                accH[t] = __builtin_amdgcn_mfma_f32_16x16x32_bf16(af, kHreg[ws], accH[t], 0, 0, 0);
            }
        }
    }

    // ---- write partials (one 2048-float record per block, per branch) ----
    const size_t pb = (size_t)bid * 2048;
    #pragma unroll
    for (int t = 0; t < 2; ++t) {
        #pragma unroll
        for (int r = 0; r < 4; ++r) {
            const int h = (wv*2 + t)*16 + lc*4 + r;
            PH[pb + (size_t)h*16 + lr] = accH[t][r];
            const int k = lc*4 + r;
            const int w = (wv*2 + t)*16 + lr;
            PW[pb + (size_t)k*128 + w] = accW[t][r];
        }
    }
}

// ============ Kernel 2: reduce partials (64 grp-chunks) -> energy[8][4096] ====
// grid 512, block 256: block owns 64 outputs; 4-way split + per-block minmax.
__global__ __launch_bounds__(256) void energy_reduce(
    const float* __restrict__ PH, const float* __restrict__ PW,
    float* __restrict__ energy, float* __restrict__ bmin, float* __restrict__ bmax)
{
    const int bidx = blockIdx.x;           // 0..511
    const int tid  = threadIdx.x;
    const int ol   = tid & 63, qd = tid >> 6;
    const int o    = bidx*64 + ol;         // 0..32767
    __shared__ float red[4][64];

    const int isW = o >> 14;               // 0: PH, 1: PW
    const int oo  = o & 16383;
    const int b   = oo >> 11, i = oo & 2047;
    const float* P = (isW ? PW : PH) + (size_t)b*2048 + i;
    float s = 0.f;
    #pragma unroll
    for (int j = 0; j < 16; ++j)
        s += P[(size_t)(qd*16 + j) * 16384];       // grp stride = 8 blocks * 2048
    red[qd][ol] = s;
    __syncthreads();

    if (tid < 64) {
        float v = red[0][tid] + red[1][tid] + red[2][tid] + red[3][tid];
        const int o2 = bidx*64 + tid;
        const int oo2 = o2 & 16383;
        const int b2 = oo2 >> 11, i2 = oo2 & 2047;
        const size_t dst = (o2 >> 14)
            ? ((size_t)b2*4096 + 2048 + (size_t)(i2 & 127)*16 + (i2 >> 7))
            : ((size_t)b2*4096 + i2);
        energy[dst] = v;
        float mn = v, mx = v;
        #pragma unroll
        for (int sft = 32; sft > 0; sft >>= 1) {
            mn = fminf(mn, __shfl_xor(mn, sft));
            mx = fmaxf(mx, __shfl_xor(mx, sft));
        }
        if (tid == 0) { bmin[bidx] = mn; bmax[bidx] = mx; }
    }
}

// ============ Kernel 3: softmax (8 blocks, one row each) ============
__global__ __launch_bounds__(1024) void softmax_kernel(
    const float* __restrict__ energy, const float* __restrict__ bmin,
    const float* __restrict__ bmax, float* __restrict__ att)
{
    const int b = blockIdx.x, tid = threadIdx.x;
    const int lane = tid & 63, wid = tid >> 6;     // 16 waves
    __shared__ float smn[16], smx[16], sred[16], bc2[2];

    float mn = 3.0e38f, mx = -3.0e38f;
    if (tid < 512) { mn = bmin[tid]; mx = bmax[tid]; }
    #pragma unroll
    for (int s = 32; s > 0; s >>= 1) {
        mn = fminf(mn, __shfl_xor(mn, s));
        mx = fmaxf(mx, __shfl_xor(mx, s));
    }
    if (lane == 0) { smn[wid] = mn; smx[wid] = mx; }
    __syncthreads();
    if (tid == 0) {
        float a = smn[0], m = smx[0];
        #pragma unroll
        for (int i = 1; i < 16; ++i) { a = fminf(a, smn[i]); m = fmaxf(m, smx[i]); }
        bc2[0] = a; bc2[1] = m;
    }
    __syncthreads();
    const float gmn = bc2[0];
    const float inv = 1.0f / (bc2[1] - gmn);

    float4 v = ((const float4*)energy)[b*1024 + tid];
    float4 e;
    e.x = __expf((v.x - gmn) * inv);
    e.y = __expf((v.y - gmn) * inv);
    e.z = __expf((v.z - gmn) * inv);
    e.w = __expf((v.w - gmn) * inv);
    float loc = e.x + e.y + e.z + e.w;
    #pragma unroll
    for (int s = 32; s > 0; s >>= 1) loc += __shfl_down(loc, s);
    if (lane == 0) sred[wid] = loc;
    __syncthreads();
    if (tid == 0) {
        float a = 0.f;
        #pragma unroll
        for (int j = 0; j < 16; ++j) a += sred[j];
        bc2[0] = 1.0f / a;
    }
    __syncthreads();
    const float r = bc2[0];
    e.x *= r; e.y *= r; e.z *= r; e.w *= r;
    ((float4*)att)[b*1024 + tid] = e;
}

// ============ Kernel 4: recombination ============
// grid 8192 = (b = bid&7, hg = (bid>>3)&3, c = bid>>5), block 128 (w).
__global__ __launch_bounds__(128) void out_kernel(
    const float* __restrict__ t2,
    const unsigned short* __restrict__ valHbf, const float* __restrict__ valW,
    const float* __restrict__ att, float* __restrict__ out)
{
    const int bid = blockIdx.x;
    const int b  = bid & 7;
    const int hg = (bid >> 3) & 3;
    const int c  = bid >> 5;
    const int w  = threadIdx.x;
    const size_t pb = ((size_t)b * CC + c) * 2048;
    const unsigned short* vH = valHbf + pb;             // [k][w] bf16
    const float* vW = valW + pb;                        // [h][k] fp32
    const float* aH = att + (size_t)b * 4096;           // [h][16]
    const float* aW = att + (size_t)b * 4096 + 2048;    // [w][16]
    const size_t tb = ((size_t)b * CC + c) * HW;

    float vHr[16];
    #pragma unroll
    for (int k = 0; k < 16; ++k) vHr[k] = bf2f(vH[k * WW + w]);

    float aWr[16];
    {
        const float4* p = (const float4*)(aW + w * 16);
        float4 q0 = p[0], q1 = p[1], q2 = p[2], q3 = p[3];
        aWr[0]=q0.x; aWr[1]=q0.y; aWr[2]=q0.z; aWr[3]=q0.w;
        aWr[4]=q1.x; aWr[5]=q1.y; aWr[6]=q1.z; aWr[7]=q1.w;
        aWr[8]=q2.x; aWr[9]=q2.y; aWr[10]=q2.z; aWr[11]=q2.w;
        aWr[12]=q3.x; aWr[13]=q3.y; aWr[14]=q3.z; aWr[15]=q3.w;
    }

    const int hbase = hg * 32;
    #pragma unroll 2
    for (int i = 0; i < 32; ++i) {
        const int h = hbase + i;
        const float tv = t2[tb + (size_t)h * WW + w];
        const float* ah = aH + h * 16;      // wave-uniform, contiguous 64B
        const float* vw = vW + h * 16;      // wave-uniform, contiguous 64B
        float accH = 0.f, accW = 0.f;
        #pragma unroll
        for (int k = 0; k < 16; ++k) {
            accH = fmaf(vHr[k], ah[k], accH);
            accW = fmaf(aWr[k], vw[k], accW);
        }
        out[tb + (size_t)h * WW + w] = 0.5f * (accH + accW) + tv;
    }
}

extern "C" void kernel_launch(void* const* d_in, const int* in_sizes, int n_in,
                              void* d_out, int out_size, void* d_ws, size_t ws_size,
                              hipStream_t stream)
{
    const float* t1 = (const float*)d_in[0];
    const float* t2 = (const float*)d_in[1];
    float* out = (float*)d_out;
    char*  ws  = (char*)d_ws;

    unsigned short* valHbf = (unsigned short*)ws;                 //  8 MB
    float* valW   = (float*)(ws + ((size_t)8  << 20));            // 16 MB
    float* energy = (float*)(ws + ((size_t)24 << 20));            // 128 KB
    float* att    = energy + 32768;
    float* bmin   = att + 32768;
    float* bmax   = bmin + 512;

    // partials live in d_out (8.4 MB of 134 MB), overwritten by out_kernel
    float* PH = out;                        // 512*2048 floats = 4 MB
    float* PW = out + (size_t)1048576;      // 4 MB

    hipLaunchKernelGGL(fused_pool_energy, dim3(512), dim3(256), 0, stream,
                       t1, t2, valHbf, valW, PH, PW);
    hipLaunchKernelGGL(energy_reduce, dim3(512), dim3(256), 0, stream,
                       PH, PW, energy, bmin, bmax);
    hipLaunchKernelGGL(softmax_kernel, dim3(8), dim3(1024), 0, stream,
                       energy, bmin, bmax, att);
    hipLaunchKernelGGL(out_kernel, dim3(8192), dim3(128), 0, stream,
                       t2, valHbf, valW, att, out);
}

// Round 7
// 140.927 us; speedup vs baseline: 1.5778x; 1.5778x over previous
//
#include <hip/hip_runtime.h>
#include <cstddef>

#define CC 256
#define HH 128
#define WW 128
#define HW (HH*WW)          // 16384

typedef __attribute__((ext_vector_type(8))) short short8v;   // 8 bf16
typedef __attribute__((ext_vector_type(4))) float float4v;   // MFMA acc

__device__ __forceinline__ short f2bf(float x) {
    unsigned u = __float_as_uint(x);
    u += 0x7FFFu + ((u >> 16) & 1u);      // RNE to bf16
    return (short)(u >> 16);
}
__device__ __forceinline__ float4 add4(float4 a, float4 b) {
    float4 r; r.x=a.x+b.x; r.y=a.y+b.y; r.z=a.z+b.z; r.w=a.w+b.w; return r;
}
__device__ __forceinline__ float4 scale4(float4 a, float s) {
    float4 r; r.x=a.x*s; r.y=a.y*s; r.z=a.z*s; r.w=a.w*s; return r;
}
__device__ __forceinline__ float4 shflx4(float4 v, int m) {
    float4 r;
    r.x = __shfl_xor(v.x, m); r.y = __shfl_xor(v.y, m);
    r.z = __shfl_xor(v.z, m); r.w = __shfl_xor(v.w, m);
    return r;
}
__device__ __forceinline__ float hsum4(float4 v) { return v.x+v.y+v.z+v.w; }

// ============ Kernel 1: fused pooling + both energies (MFMA bf16) ============
// grid 2048: b = bid&7, c = bid>>3. block 512 (8 waves).  [R4 structure]
__global__ __launch_bounds__(512, 4) void fused_pool_energy(
    const float* __restrict__ t1, const float* __restrict__ t2,
    unsigned short* __restrict__ valHT, unsigned short* __restrict__ valWbf,
    float* __restrict__ PH, float* __restrict__ PW)
{
    __shared__ __align__(16) short t2lds[64*128];   // [h_local][w]  swz (h&7)<<3   16KB
    __shared__ __align__(16) short t2T  [128*64];   // [w][h_local]  swz ((w>>2)&7)<<3  16KB
    __shared__ __align__(16) short kH   [16*128];   // [k][w]        swz (k&7)<<3    4KB
    __shared__ __align__(16) short kWT  [16*128];   // [k][h global] swz (k&7)<<3    4KB

    const int bid = blockIdx.x;
    const int b   = bid & 7;
    const int c   = bid >> 3;
    const int tid = threadIdx.x;
    const int l   = tid & 63;
    const int wv  = tid >> 6;          // wave 0..7
    const int q   = tid & 31;          // float4 column 0..31
    const int g   = tid >> 5;          // row group 0..15
    const int bc  = b*CC + c;
    const size_t cbase = (size_t)bc * HW;
    const float4* t1c = (const float4*)(t1 + cbase);
    const float4* t2c = (const float4*)(t2 + cbase);

    // ---- issue t1 (8 rows x 1 f4-col) and t2 half0 (4 rows) loads ----
    float4 aR[8];
    #pragma unroll
    for (int r = 0; r < 8; ++r) aR[r] = t1c[g*256 + r*32 + q];
    float4 cR[4];
    #pragma unroll
    for (int r = 0; r < 4; ++r) cR[r] = t2c[g*128 + r*32 + q];

    // ---- Phase A: keys from t1 ----
    {
        float4 s = add4(add4(add4(aR[0],aR[1]), add4(aR[2],aR[3])),
                        add4(add4(aR[4],aR[5]), add4(aR[6],aR[7])));
        float4 m4 = scale4(s, 0.125f);
        short4 p; p.x=f2bf(m4.x); p.y=f2bf(m4.y); p.z=f2bf(m4.z); p.w=f2bf(m4.w);
        *(short4*)&kH[g*128 + ((q*4) ^ ((g&7)<<3))] = p;
        const int kw = q >> 1;
        const int sw = (kw & 7) << 3;
        #pragma unroll
        for (int r = 0; r < 8; ++r) {
            float rs = hsum4(aR[r]);
            rs += __shfl_xor(rs, 1);
            if ((l & 1) == 0)
                kWT[kw*128 + ((g*8+r) ^ sw)] = f2bf(rs * 0.125f);
        }
    }
    __syncthreads();

    float4v accH = {0.f,0.f,0.f,0.f};
    float4v accW = {0.f,0.f,0.f,0.f};
    float4 dR[4];

    #pragma unroll
    for (int half = 0; half < 2; ++half) {
        float4 x0, x1, x2, x3;
        if (half == 0) { x0=cR[0]; x1=cR[1]; x2=cR[2]; x3=cR[3]; }
        else           { x0=dR[0]; x1=dR[1]; x2=dR[2]; x3=dR[3]; }

        if (half == 0) {
            #pragma unroll
            for (int r = 0; r < 4; ++r) dR[r] = t2c[2048 + g*128 + r*32 + q];
        }

        // ---- pool H (8 rows via lane^32 pairing) -> valHT bf16 [w][16] ----
        {
            float4 sB = add4(add4(x0,x1), add4(x2,x3));
            float4 f8 = add4(sB, shflx4(sB, 32));
            if (l < 32) {
                const int k = half*8 + wv;
                const size_t vb = (size_t)bc * 2048;
                valHT[vb + (q*4+0)*16 + k] = (unsigned short)f2bf(f8.x * 0.125f);
                valHT[vb + (q*4+1)*16 + k] = (unsigned short)f2bf(f8.y * 0.125f);
                valHT[vb + (q*4+2)*16 + k] = (unsigned short)f2bf(f8.z * 0.125f);
                valHT[vb + (q*4+3)*16 + k] = (unsigned short)f2bf(f8.w * 0.125f);
            }
        }
        // ---- pool W -> valWbf bf16 [h][16] (even lanes) ----
        {
            const int kw = q >> 1;
            float r0 = hsum4(x0), r1 = hsum4(x1), r2 = hsum4(x2), r3 = hsum4(x3);
            r0 += __shfl_xor(r0, 1); r1 += __shfl_xor(r1, 1);
            r2 += __shfl_xor(r2, 1); r3 += __shfl_xor(r3, 1);
            if ((l & 1) == 0) {
                const size_t vb = (size_t)bc*2048 + (size_t)(half*64 + g*4)*16 + kw;
                valWbf[vb +  0] = (unsigned short)f2bf(r0 * 0.125f);
                valWbf[vb + 16] = (unsigned short)f2bf(r1 * 0.125f);
                valWbf[vb + 32] = (unsigned short)f2bf(r2 * 0.125f);
                valWbf[vb + 48] = (unsigned short)f2bf(r3 * 0.125f);
            }
        }
        // ---- stage LDS: row-major + transposed (bf16) ----
        short4 s0, s1, s2, s3;
        s0.x=f2bf(x0.x); s0.y=f2bf(x0.y); s0.z=f2bf(x0.z); s0.w=f2bf(x0.w);
        s1.x=f2bf(x1.x); s1.y=f2bf(x1.y); s1.z=f2bf(x1.z); s1.w=f2bf(x1.w);
        s2.x=f2bf(x2.x); s2.y=f2bf(x2.y); s2.z=f2bf(x2.z); s2.w=f2bf(x2.w);
        s3.x=f2bf(x3.x); s3.y=f2bf(x3.y); s3.z=f2bf(x3.z); s3.w=f2bf(x3.w);
        {
            const int hl0 = g*4;
            *(short4*)&t2lds[(hl0+0)*128 + ((q*4) ^ (((hl0+0)&7)<<3))] = s0;
            *(short4*)&t2lds[(hl0+1)*128 + ((q*4) ^ (((hl0+1)&7)<<3))] = s1;
            *(short4*)&t2lds[(hl0+2)*128 + ((q*4) ^ (((hl0+2)&7)<<3))] = s2;
            *(short4*)&t2lds[(hl0+3)*128 + ((q*4) ^ (((hl0+3)&7)<<3))] = s3;
            const int swt = (q & 7) << 3;
            const int hb  = hl0 ^ swt;
            short4 p;
            p.x=s0.x; p.y=s1.x; p.z=s2.x; p.w=s3.x;
            *(short4*)&t2T[(q*4+0)*64 + hb] = p;
            p.x=s0.y; p.y=s1.y; p.z=s2.y; p.w=s3.y;
            *(short4*)&t2T[(q*4+1)*64 + hb] = p;
            p.x=s0.z; p.y=s1.z; p.z=s2.z; p.w=s3.z;
            *(short4*)&t2T[(q*4+2)*64 + hb] = p;
            p.x=s0.w; p.y=s1.w; p.z=s2.w; p.w=s3.w;
            *(short4*)&t2T[(q*4+3)*64 + hb] = p;
        }
        __syncthreads();

        // ---- MFMA H branch ----
        if ((wv >> 2) == half) {
            const int hl = (wv & 3)*16 + (l & 15);
            const int kb = l & 15;
            #pragma unroll
            for (int ws2 = 0; ws2 < 4; ++ws2) {
                const int wb = ws2*32 + (l>>4)*8;
                short8v A = *(const short8v*)&t2lds[hl*128 + (wb ^ ((hl&7)<<3))];
                short8v B = *(const short8v*)&kH  [kb*128 + (wb ^ ((kb&7)<<3))];
                accH = __builtin_amdgcn_mfma_f32_16x16x32_bf16(A, B, accH, 0, 0, 0);
            }
        }
        // ---- MFMA W branch ----
        {
            const int kb = l & 15;
            const int w  = wv*16 + (l & 15);
            const int swt = ((w >> 2) & 7) << 3;
            #pragma unroll
            for (int hs = 0; hs < 2; ++hs) {
                const int hloc = hs*32 + (l>>4)*8;
                const int hg   = half*64 + hloc;
                short8v A = *(const short8v*)&kWT[kb*128 + (hg ^ ((kb&7)<<3))];
                short8v B = *(const short8v*)&t2T[w*64   + (hloc ^ swt)];
                accW = __builtin_amdgcn_mfma_f32_16x16x32_bf16(A, B, accW, 0, 0, 0);
            }
        }
        __syncthreads();
    }

    // ---------- write partials ----------
    {
        const size_t pb = (size_t)bc * 2048;
        #pragma unroll
        for (int r = 0; r < 4; ++r) {
            const int h = wv*16 + (l>>4)*4 + r;
            PH[pb + h*16 + (l&15)] = accH[r];
            const int k = (l>>4)*4 + r;
            PW[pb + k*128 + wv*16 + (l&15)] = accW[r];
        }
    }
}

// ============ Kernel 2: reduce partials (256 c-chunks) -> energy[8][4096] ============
__global__ __launch_bounds__(256) void energy_reduce(
    const float* __restrict__ PH, const float* __restrict__ PW,
    float* __restrict__ energy, float* __restrict__ bmin, float* __restrict__ bmax)
{
    const int bidx = blockIdx.x;           // 0..511
    const int tid  = threadIdx.x;
    const int ol   = tid & 63, qd = tid >> 6;
    const int o    = bidx*64 + ol;         // 0..32767
    __shared__ float red[4][64];

    const int isW = o >> 14;
    const int oo  = o & 16383;
    const int b   = oo >> 11, i = oo & 2047;
    const float* P = (isW ? PW : PH) + (size_t)b*256*2048 + i;
    float s = 0.f;
    #pragma unroll 8
    for (int j = 0; j < 64; ++j) s += P[(size_t)(qd*64 + j)*2048];
    red[qd][ol] = s;
    __syncthreads();

    if (tid < 64) {
        float v = red[0][tid] + red[1][tid] + red[2][tid] + red[3][tid];
        const int o2 = bidx*64 + tid;
        const int oo2 = o2 & 16383;
        const int b2 = oo2 >> 11, i2 = oo2 & 2047;
        const size_t dst = (o2 >> 14)
            ? ((size_t)b2*4096 + 2048 + (size_t)(i2 & 127)*16 + (i2 >> 7))
            : ((size_t)b2*4096 + i2);
        energy[dst] = v;
        float mn = v, mx = v;
        #pragma unroll
        for (int sft = 32; sft > 0; sft >>= 1) {
            mn = fminf(mn, __shfl_xor(mn, sft));
            mx = fmaxf(mx, __shfl_xor(mx, sft));
        }
        if (tid == 0) { bmin[bidx] = mn; bmax[bidx] = mx; }
    }
}

// ============ Kernel 3: softmax (8 blocks) -> bf16 att in [h][16] and [w][16] ====
__global__ __launch_bounds__(1024) void softmax_kernel(
    const float* __restrict__ energy, const float* __restrict__ bmin,
    const float* __restrict__ bmax,
    unsigned short* __restrict__ aHbf, unsigned short* __restrict__ aWbf)
{
    const int b = blockIdx.x, tid = threadIdx.x;
    const int lane = tid & 63, wid = tid >> 6;     // 16 waves
    __shared__ float smn[16], smx[16], sred[16], bc2[2];

    float mn = 3.0e38f, mx = -3.0e38f;
    if (tid < 512) { mn = bmin[tid]; mx = bmax[tid]; }
    #pragma unroll
    for (int s = 32; s > 0; s >>= 1) {
        mn = fminf(mn, __shfl_xor(mn, s));
        mx = fmaxf(mx, __shfl_xor(mx, s));
    }
    if (lane == 0) { smn[wid] = mn; smx[wid] = mx; }
    __syncthreads();
    if (tid == 0) {
        float a = smn[0], m = smx[0];
        #pragma unroll
        for (int i = 1; i < 16; ++i) { a = fminf(a, smn[i]); m = fmaxf(m, smx[i]); }
        bc2[0] = a; bc2[1] = m;
    }
    __syncthreads();
    const float gmn = bc2[0];
    const float inv = 1.0f / (bc2[1] - gmn);

    float4 v = ((const float4*)energy)[b*1024 + tid];
    float4 e;
    e.x = __expf((v.x - gmn) * inv);
    e.y = __expf((v.y - gmn) * inv);
    e.z = __expf((v.z - gmn) * inv);
    e.w = __expf((v.w - gmn) * inv);
    float loc = e.x + e.y + e.z + e.w;
    #pragma unroll
    for (int s = 32; s > 0; s >>= 1) loc += __shfl_down(loc, s);
    if (lane == 0) sred[wid] = loc;
    __syncthreads();
    if (tid == 0) {
        float a = 0.f;
        #pragma unroll
        for (int j = 0; j < 16; ++j) a += sred[j];
        bc2[0] = 1.0f / a;
    }
    __syncthreads();
    const float r = bc2[0];
    short4 p;
    p.x = f2bf(e.x * r); p.y = f2bf(e.y * r);
    p.z = f2bf(e.z * r); p.w = f2bf(e.w * r);
    if (tid < 512)
        *(short4*)&aHbf[(size_t)b*2048 + tid*4] = p;
    else
        *(short4*)&aWbf[(size_t)b*2048 + (tid-512)*4] = p;
}

// ============ Kernel 4: recombination via rank-32 MFMA ============
// grid 2048 (b = bid&7, c = bid>>3), block 256 (4 waves).
// out[h][w] = 0.5 * mfma32([aH[h]|vW[h]], [valHT[w]|aW[w]]) + t2[h][w].
__global__ __launch_bounds__(256) void out_kernel(
    const float* __restrict__ t2,
    const unsigned short* __restrict__ valHT,   // [b][c][w][16]
    const unsigned short* __restrict__ valWbf,  // [b][c][h][16]
    const unsigned short* __restrict__ aHbf,    // [b][h][16]
    const unsigned short* __restrict__ aWbf,    // [b][w][16]
    float* __restrict__ out)
{
    const int bid = blockIdx.x;
    const int b = bid & 7, c = bid >> 3;
    const int bc = b*CC + c;
    const int tid = threadIdx.x;
    const int l  = tid & 63;
    const int wv = tid >> 6;       // 0..3
    const int ln = l & 15;
    const int q4 = l >> 4;         // k-quadrant
    const size_t tb = (size_t)bc * HW;

    const unsigned short* vHT = valHT  + (size_t)bc*2048;   // [w][16]
    const unsigned short* vW  = valWbf + (size_t)bc*2048;   // [h][16]
    const unsigned short* aH  = aHbf + (size_t)b*2048;      // [h][16]
    const unsigned short* aW  = aWbf + (size_t)b*2048;      // [w][16]

    // B-frags for all 8 w-tiles: k<16 -> valHT row w, k>=16 -> aW row w
    short8v Bf[8];
    {
        const unsigned short* src = (q4 < 2) ? vHT : aW;
        #pragma unroll
        for (int tw = 0; tw < 8; ++tw)
            Bf[tw] = *(const short8v*)&src[(tw*16 + ln)*16 + (q4 & 1)*8];
    }

    #pragma unroll
    for (int t = 0; t < 2; ++t) {
        const int th = wv*2 + t;
        const unsigned short* asrc = (q4 < 2) ? aH : vW;
        short8v Af = *(const short8v*)&asrc[(th*16 + ln)*16 + (q4 & 1)*8];
        #pragma unroll
        for (int tw = 0; tw < 8; ++tw) {
            float4v acc = {0.f,0.f,0.f,0.f};
            acc = __builtin_amdgcn_mfma_f32_16x16x32_bf16(Af, Bf[tw], acc, 0, 0, 0);
            const size_t base = tb + (size_t)(th*16 + q4*4)*128 + tw*16 + ln;
            #pragma unroll
            for (int r = 0; r < 4; ++r) {
                const float tv = t2[base + (size_t)r*128];
                out[base + (size_t)r*128] = fmaf(0.5f, acc[r], tv);
            }
        }
    }
}

extern "C" void kernel_launch(void* const* d_in, const int* in_sizes, int n_in,
                              void* d_out, int out_size, void* d_ws, size_t ws_size,
                              hipStream_t stream)
{
    const float* t1 = (const float*)d_in[0];
    const float* t2 = (const float*)d_in[1];
    float* out = (float*)d_out;
    char*  ws  = (char*)d_ws;

    unsigned short* valHT  = (unsigned short*)ws;                       // 8 MB
    unsigned short* valWbf = (unsigned short*)(ws + ((size_t)8 << 20)); // 8 MB
    float* energy = (float*)(ws + ((size_t)16 << 20));                  // 128 KB
    float* bmin   = energy + 32768;
    float* bmax   = bmin + 512;
    unsigned short* aHbf = (unsigned short*)(ws + ((size_t)17 << 20));  // 32 KB
    unsigned short* aWbf = aHbf + 8*2048;                               // 32 KB

    // partials live in d_out (32 MB of 134 MB), overwritten by out_kernel
    float* PH = out;                        // 2048*2048 floats = 16 MB
    float* PW = out + (size_t)4194304;      // 16 MB

    hipLaunchKernelGGL(fused_pool_energy, dim3(2048), dim3(512), 0, stream,
                       t1, t2, valHT, valWbf, PH, PW);
    hipLaunchKernelGGL(energy_reduce, dim3(512), dim3(256), 0, stream,
                       PH, PW, energy, bmin, bmax);
    hipLaunchKernelGGL(softmax_kernel, dim3(8), dim3(1024), 0, stream,
                       energy, bmin, bmax, aHbf, aWbf);
    hipLaunchKernelGGL(out_kernel, dim3(2048), dim3(256), 0, stream,
                       t2, valHT, valWbf, aHbf, aWbf, out);
}

// Round 8
// 137.435 us; speedup vs baseline: 1.6179x; 1.0254x over previous
//
#include <hip/hip_runtime.h>
#include <cstddef>

#define CC 256
#define HH 128
#define WW 128
#define HW (HH*WW)          // 16384

typedef __attribute__((ext_vector_type(8))) short short8v;   // 8 bf16
typedef __attribute__((ext_vector_type(4))) float float4v;   // MFMA acc

__device__ __forceinline__ short f2bf(float x) {
    unsigned u = __float_as_uint(x);
    u += 0x7FFFu + ((u >> 16) & 1u);      // RNE to bf16
    return (short)(u >> 16);
}
__device__ __forceinline__ float4 add4(float4 a, float4 b) {
    float4 r; r.x=a.x+b.x; r.y=a.y+b.y; r.z=a.z+b.z; r.w=a.w+b.w; return r;
}
__device__ __forceinline__ float4 scale4(float4 a, float s) {
    float4 r; r.x=a.x*s; r.y=a.y*s; r.z=a.z*s; r.w=a.w*s; return r;
}
__device__ __forceinline__ float4 shflx4(float4 v, int m) {
    float4 r;
    r.x = __shfl_xor(v.x, m); r.y = __shfl_xor(v.y, m);
    r.z = __shfl_xor(v.z, m); r.w = __shfl_xor(v.w, m);
    return r;
}
__device__ __forceinline__ float hsum4(float4 v) { return v.x+v.y+v.z+v.w; }

// issue a 16B global load at a pinned program point (compiler cannot sink it)
#define GLD4(dst, addr, OFFSTR) \
    asm volatile("global_load_dwordx4 %0, %1, off offset:" OFFSTR \
                 : "=v"(dst) : "v"(addr) : "memory")

#define WAITVM(NSTR) { asm volatile("s_waitcnt vmcnt(" NSTR ")" ::: "memory"); \
                       __builtin_amdgcn_sched_barrier(0); }
// barrier that waits only LDS (keeps global loads/stores in flight)
#define BAR_LDS { asm volatile("s_waitcnt lgkmcnt(0)" ::: "memory"); \
                  __builtin_amdgcn_sched_barrier(0); \
                  __builtin_amdgcn_s_barrier(); }

// ============ Kernel 1: fused pooling + both energies (MFMA bf16) ============
// grid 2048: b = bid&7, c = bid>>3. block 512 (8 waves).
// All 16 global loads issued via inline asm at block start; counted vmcnt.
__global__ __launch_bounds__(512, 4) void fused_pool_energy(
    const float* __restrict__ t1, const float* __restrict__ t2,
    unsigned short* __restrict__ valHT, unsigned short* __restrict__ valWbf,
    float* __restrict__ PH, float* __restrict__ PW)
{
    __shared__ __align__(16) short t2lds[64*128];   // [h_local][w]  swz (h&7)<<3   16KB
    __shared__ __align__(16) short t2T  [128*64];   // [w][h_local]  swz ((w>>2)&7)<<3  16KB
    __shared__ __align__(16) short kH   [16*128];   // [k][w]        swz (k&7)<<3    4KB
    __shared__ __align__(16) short kWT  [16*128];   // [k][h global] swz (k&7)<<3    4KB

    const int bid = blockIdx.x;
    const int b   = bid & 7;
    const int c   = bid >> 3;
    const int tid = threadIdx.x;
    const int l   = tid & 63;
    const int wv  = tid >> 6;          // wave 0..7
    const int q   = tid & 31;          // float4 column 0..31
    const int g   = tid >> 5;          // row group 0..15
    const int bc  = b*CC + c;
    const size_t cbase = (size_t)bc * HW;
    const float4* t1c = (const float4*)(t1 + cbase);
    const float4* t2c = (const float4*)(t2 + cbase);

    // ---- issue ALL loads up front: t1 (8), t2 half0 (4), t2 half1 (4) ----
    const float4* ap = t1c + g*256 + q;       // t1 rows g*8..g*8+7, f4-col q
    const float4* cp = t2c + g*128 + q;       // t2 rows g*4..g*4+3 (half 0)
    const float4* dp = cp + 2048;             // t2 half 1
    float4 aR[8], cR[4], dR[4];
    GLD4(aR[0], ap, "0");    GLD4(aR[1], ap, "512");
    GLD4(aR[2], ap, "1024"); GLD4(aR[3], ap, "1536");
    GLD4(aR[4], ap, "2048"); GLD4(aR[5], ap, "2560");
    GLD4(aR[6], ap, "3072"); GLD4(aR[7], ap, "3584");
    GLD4(cR[0], cp, "0");    GLD4(cR[1], cp, "512");
    GLD4(cR[2], cp, "1024"); GLD4(cR[3], cp, "1536");
    GLD4(dR[0], dp, "0");    GLD4(dR[1], dp, "512");
    GLD4(dR[2], dp, "1024"); GLD4(dR[3], dp, "1536");

    // ---- Phase A: keys from t1 (needs only aR: 8 loads still outstanding) ----
    WAITVM("8");
    {
        float4 s = add4(add4(add4(aR[0],aR[1]), add4(aR[2],aR[3])),
                        add4(add4(aR[4],aR[5]), add4(aR[6],aR[7])));
        float4 m4 = scale4(s, 0.125f);
        short4 p; p.x=f2bf(m4.x); p.y=f2bf(m4.y); p.z=f2bf(m4.z); p.w=f2bf(m4.w);
        *(short4*)&kH[g*128 + ((q*4) ^ ((g&7)<<3))] = p;
        const int kw = q >> 1;
        const int sw = (kw & 7) << 3;
        #pragma unroll
        for (int r = 0; r < 8; ++r) {
            float rs = hsum4(aR[r]);
            rs += __shfl_xor(rs, 1);
            if ((l & 1) == 0)
                kWT[kw*128 + ((g*8+r) ^ sw)] = f2bf(rs * 0.125f);
        }
    }
    BAR_LDS;

    float4v accH = {0.f,0.f,0.f,0.f};
    float4v accW = {0.f,0.f,0.f,0.f};

    WAITVM("0");     // both t2 halves landed (issued together; one exposure)

    #pragma unroll
    for (int half = 0; half < 2; ++half) {
        float4 x0, x1, x2, x3;
        if (half == 0) { x0=cR[0]; x1=cR[1]; x2=cR[2]; x3=cR[3]; }
        else           { x0=dR[0]; x1=dR[1]; x2=dR[2]; x3=dR[3]; }

        // ---- pool H (8 rows via lane^32 pairing) -> valHT bf16 [w][16] ----
        {
            float4 sB = add4(add4(x0,x1), add4(x2,x3));
            float4 f8 = add4(sB, shflx4(sB, 32));
            if (l < 32) {
                const int k = half*8 + wv;
                const size_t vb = (size_t)bc * 2048;
                valHT[vb + (q*4+0)*16 + k] = (unsigned short)f2bf(f8.x * 0.125f);
                valHT[vb + (q*4+1)*16 + k] = (unsigned short)f2bf(f8.y * 0.125f);
                valHT[vb + (q*4+2)*16 + k] = (unsigned short)f2bf(f8.z * 0.125f);
                valHT[vb + (q*4+3)*16 + k] = (unsigned short)f2bf(f8.w * 0.125f);
            }
        }
        // ---- pool W -> valWbf bf16 [h][16] (even lanes) ----
        {
            const int kw = q >> 1;
            float r0 = hsum4(x0), r1 = hsum4(x1), r2 = hsum4(x2), r3 = hsum4(x3);
            r0 += __shfl_xor(r0, 1); r1 += __shfl_xor(r1, 1);
            r2 += __shfl_xor(r2, 1); r3 += __shfl_xor(r3, 1);
            if ((l & 1) == 0) {
                const size_t vb = (size_t)bc*2048 + (size_t)(half*64 + g*4)*16 + kw;
                valWbf[vb +  0] = (unsigned short)f2bf(r0 * 0.125f);
                valWbf[vb + 16] = (unsigned short)f2bf(r1 * 0.125f);
                valWbf[vb + 32] = (unsigned short)f2bf(r2 * 0.125f);
                valWbf[vb + 48] = (unsigned short)f2bf(r3 * 0.125f);
            }
        }
        // ---- stage LDS: row-major + transposed (bf16) ----
        short4 s0, s1, s2, s3;
        s0.x=f2bf(x0.x); s0.y=f2bf(x0.y); s0.z=f2bf(x0.z); s0.w=f2bf(x0.w);
        s1.x=f2bf(x1.x); s1.y=f2bf(x1.y); s1.z=f2bf(x1.z); s1.w=f2bf(x1.w);
        s2.x=f2bf(x2.x); s2.y=f2bf(x2.y); s2.z=f2bf(x2.z); s2.w=f2bf(x2.w);
        s3.x=f2bf(x3.x); s3.y=f2bf(x3.y); s3.z=f2bf(x3.z); s3.w=f2bf(x3.w);
        {
            const int hl0 = g*4;
            *(short4*)&t2lds[(hl0+0)*128 + ((q*4) ^ (((hl0+0)&7)<<3))] = s0;
            *(short4*)&t2lds[(hl0+1)*128 + ((q*4) ^ (((hl0+1)&7)<<3))] = s1;
            *(short4*)&t2lds[(hl0+2)*128 + ((q*4) ^ (((hl0+2)&7)<<3))] = s2;
            *(short4*)&t2lds[(hl0+3)*128 + ((q*4) ^ (((hl0+3)&7)<<3))] = s3;
            const int swt = (q & 7) << 3;
            const int hb  = hl0 ^ swt;
            short4 p;
            p.x=s0.x; p.y=s1.x; p.z=s2.x; p.w=s3.x;
            *(short4*)&t2T[(q*4+0)*64 + hb] = p;
            p.x=s0.y; p.y=s1.y; p.z=s2.y; p.w=s3.y;
            *(short4*)&t2T[(q*4+1)*64 + hb] = p;
            p.x=s0.z; p.y=s1.z; p.z=s2.z; p.w=s3.z;
            *(short4*)&t2T[(q*4+2)*64 + hb] = p;
            p.x=s0.w; p.y=s1.w; p.z=s2.w; p.w=s3.w;
            *(short4*)&t2T[(q*4+3)*64 + hb] = p;
        }
        BAR_LDS;   // tiles visible; global stores keep flying

        // ---- MFMA H branch ----
        if ((wv >> 2) == half) {
            const int hl = (wv & 3)*16 + (l & 15);
            const int kb = l & 15;
            #pragma unroll
            for (int ws2 = 0; ws2 < 4; ++ws2) {
                const int wb = ws2*32 + (l>>4)*8;
                short8v A = *(const short8v*)&t2lds[hl*128 + (wb ^ ((hl&7)<<3))];
                short8v B = *(const short8v*)&kH  [kb*128 + (wb ^ ((kb&7)<<3))];
                accH = __builtin_amdgcn_mfma_f32_16x16x32_bf16(A, B, accH, 0, 0, 0);
            }
        }
        // ---- MFMA W branch ----
        {
            const int kb = l & 15;
            const int w  = wv*16 + (l & 15);
            const int swt = ((w >> 2) & 7) << 3;
            #pragma unroll
            for (int hs = 0; hs < 2; ++hs) {
                const int hloc = hs*32 + (l>>4)*8;
                const int hg   = half*64 + hloc;
                short8v A = *(const short8v*)&kWT[kb*128 + (hg ^ ((kb&7)<<3))];
                short8v B = *(const short8v*)&t2T[w*64   + (hloc ^ swt)];
                accW = __builtin_amdgcn_mfma_f32_16x16x32_bf16(A, B, accW, 0, 0, 0);
            }
        }
        BAR_LDS;   // all fragment reads retired before next half's staging
    }

    // ---------- write partials ----------
    {
        const size_t pb = (size_t)bc * 2048;
        #pragma unroll
        for (int r = 0; r < 4; ++r) {
            const int h = wv*16 + (l>>4)*4 + r;
            PH[pb + h*16 + (l&15)] = accH[r];
            const int k = (l>>4)*4 + r;
            PW[pb + k*128 + wv*16 + (l&15)] = accW[r];
        }
    }
}

// ============ Kernel 2: reduce partials (256 c-chunks) -> energy[8][4096] ============
__global__ __launch_bounds__(256) void energy_reduce(
    const float* __restrict__ PH, const float* __restrict__ PW,
    float* __restrict__ energy, float* __restrict__ bmin, float* __restrict__ bmax)
{
    const int bidx = blockIdx.x;           // 0..511
    const int tid  = threadIdx.x;
    const int ol   = tid & 63, qd = tid >> 6;
    const int o    = bidx*64 + ol;         // 0..32767
    __shared__ float red[4][64];

    const int isW = o >> 14;
    const int oo  = o & 16383;
    const int b   = oo >> 11, i = oo & 2047;
    const float* P = (isW ? PW : PH) + (size_t)b*256*2048 + i;
    float s = 0.f;
    #pragma unroll 8
    for (int j = 0; j < 64; ++j) s += P[(size_t)(qd*64 + j)*2048];
    red[qd][ol] = s;
    __syncthreads();

    if (tid < 64) {
        float v = red[0][tid] + red[1][tid] + red[2][tid] + red[3][tid];
        const int o2 = bidx*64 + tid;
        const int oo2 = o2 & 16383;
        const int b2 = oo2 >> 11, i2 = oo2 & 2047;
        const size_t dst = (o2 >> 14)
            ? ((size_t)b2*4096 + 2048 + (size_t)(i2 & 127)*16 + (i2 >> 7))
            : ((size_t)b2*4096 + i2);
        energy[dst] = v;
        float mn = v, mx = v;
        #pragma unroll
        for (int sft = 32; sft > 0; sft >>= 1) {
            mn = fminf(mn, __shfl_xor(mn, sft));
            mx = fmaxf(mx, __shfl_xor(mx, sft));
        }
        if (tid == 0) { bmin[bidx] = mn; bmax[bidx] = mx; }
    }
}

// ============ Kernel 3: softmax (8 blocks) -> bf16 att in [h][16] and [w][16] ====
__global__ __launch_bounds__(1024) void softmax_kernel(
    const float* __restrict__ energy, const float* __restrict__ bmin,
    const float* __restrict__ bmax,
    unsigned short* __restrict__ aHbf, unsigned short* __restrict__ aWbf)
{
    const int b = blockIdx.x, tid = threadIdx.x;
    const int lane = tid & 63, wid = tid >> 6;     // 16 waves
    __shared__ float smn[16], smx[16], sred[16], bc2[2];

    float mn = 3.0e38f, mx = -3.0e38f;
    if (tid < 512) { mn = bmin[tid]; mx = bmax[tid]; }
    #pragma unroll
    for (int s = 32; s > 0; s >>= 1) {
        mn = fminf(mn, __shfl_xor(mn, s));
        mx = fmaxf(mx, __shfl_xor(mx, s));
    }
    if (lane == 0) { smn[wid] = mn; smx[wid] = mx; }
    __syncthreads();
    if (tid == 0) {
        float a = smn[0], m = smx[0];
        #pragma unroll
        for (int i = 1; i < 16; ++i) { a = fminf(a, smn[i]); m = fmaxf(m, smx[i]); }
        bc2[0] = a; bc2[1] = m;
    }
    __syncthreads();
    const float gmn = bc2[0];
    const float inv = 1.0f / (bc2[1] - gmn);

    float4 v = ((const float4*)energy)[b*1024 + tid];
    float4 e;
    e.x = __expf((v.x - gmn) * inv);
    e.y = __expf((v.y - gmn) * inv);
    e.z = __expf((v.z - gmn) * inv);
    e.w = __expf((v.w - gmn) * inv);
    float loc = e.x + e.y + e.z + e.w;
    #pragma unroll
    for (int s = 32; s > 0; s >>= 1) loc += __shfl_down(loc, s);
    if (lane == 0) sred[wid] = loc;
    __syncthreads();
    if (tid == 0) {
        float a = 0.f;
        #pragma unroll
        for (int j = 0; j < 16; ++j) a += sred[j];
        bc2[0] = 1.0f / a;
    }
    __syncthreads();
    const float r = bc2[0];
    short4 p;
    p.x = f2bf(e.x * r); p.y = f2bf(e.y * r);
    p.z = f2bf(e.z * r); p.w = f2bf(e.w * r);
    if (tid < 512)
        *(short4*)&aHbf[(size_t)b*2048 + tid*4] = p;
    else
        *(short4*)&aWbf[(size_t)b*2048 + (tid-512)*4] = p;
}

// ============ Kernel 4: recombination via rank-32 MFMA ============
// grid 2048 (b = bid&7, c = bid>>3), block 256 (4 waves).
__global__ __launch_bounds__(256) void out_kernel(
    const float* __restrict__ t2,
    const unsigned short* __restrict__ valHT,   // [b][c][w][16]
    const unsigned short* __restrict__ valWbf,  // [b][c][h][16]
    const unsigned short* __restrict__ aHbf,    // [b][h][16]
    const unsigned short* __restrict__ aWbf,    // [b][w][16]
    float* __restrict__ out)
{
    const int bid = blockIdx.x;
    const int b = bid & 7, c = bid >> 3;
    const int bc = b*CC + c;
    const int tid = threadIdx.x;
    const int l  = tid & 63;
    const int wv = tid >> 6;       // 0..3
    const int ln = l & 15;
    const int q4 = l >> 4;         // k-quadrant
    const size_t tb = (size_t)bc * HW;

    const unsigned short* vHT = valHT  + (size_t)bc*2048;   // [w][16]
    const unsigned short* vW  = valWbf + (size_t)bc*2048;   // [h][16]
    const unsigned short* aH  = aHbf + (size_t)b*2048;      // [h][16]
    const unsigned short* aW  = aWbf + (size_t)b*2048;      // [w][16]

    short8v Bf[8];
    {
        const unsigned short* src = (q4 < 2) ? vHT : aW;
        #pragma unroll
        for (int tw = 0; tw < 8; ++tw)
            Bf[tw] = *(const short8v*)&src[(tw*16 + ln)*16 + (q4 & 1)*8];
    }

    #pragma unroll
    for (int t = 0; t < 2; ++t) {
        const int th = wv*2 + t;
        const unsigned short* asrc = (q4 < 2) ? aH : vW;
        short8v Af = *(const short8v*)&asrc[(th*16 + ln)*16 + (q4 & 1)*8];
        #pragma unroll
        for (int tw = 0; tw < 8; ++tw) {
            float4v acc = {0.f,0.f,0.f,0.f};
            acc = __builtin_amdgcn_mfma_f32_16x16x32_bf16(Af, Bf[tw], acc, 0, 0, 0);
            const size_t base = tb + (size_t)(th*16 + q4*4)*128 + tw*16 + ln;
            #pragma unroll
            for (int r = 0; r < 4; ++r) {
                const float tv = t2[base + (size_t)r*128];
                out[base + (size_t)r*128] = fmaf(0.5f, acc[r], tv);
            }
        }
    }
}

extern "C" void kernel_launch(void* const* d_in, const int* in_sizes, int n_in,
                              void* d_out, int out_size, void* d_ws, size_t ws_size,
                              hipStream_t stream)
{
    const float* t1 = (const float*)d_in[0];
    const float* t2 = (const float*)d_in[1];
    float* out = (float*)d_out;
    char*  ws  = (char*)d_ws;

    unsigned short* valHT  = (unsigned short*)ws;                       // 8 MB
    unsigned short* valWbf = (unsigned short*)(ws + ((size_t)8 << 20)); // 8 MB
    float* energy = (float*)(ws + ((size_t)16 << 20));                  // 128 KB
    float* bmin   = energy + 32768;
    float* bmax   = bmin + 512;
    unsigned short* aHbf = (unsigned short*)(ws + ((size_t)17 << 20));  // 32 KB
    unsigned short* aWbf = aHbf + 8*2048;                               // 32 KB

    // partials live in d_out (32 MB of 134 MB), overwritten by out_kernel
    float* PH = out;                        // 2048*2048 floats = 16 MB
    float* PW = out + (size_t)4194304;      // 16 MB

    hipLaunchKernelGGL(fused_pool_energy, dim3(2048), dim3(512), 0, stream,
                       t1, t2, valHT, valWbf, PH, PW);
    hipLaunchKernelGGL(energy_reduce, dim3(512), dim3(256), 0, stream,
                       PH, PW, energy, bmin, bmax);
    hipLaunchKernelGGL(softmax_kernel, dim3(8), dim3(1024), 0, stream,
                       energy, bmin, bmax, aHbf, aWbf);
    hipLaunchKernelGGL(out_kernel, dim3(2048), dim3(256), 0, stream,
                       t2, valHT, valWbf, aHbf, aWbf, out);
}